// Round 2
// 826.495 us; speedup vs baseline: 1.1987x; 1.1987x over previous
//
#include <hip/hip_runtime.h>

typedef __attribute__((ext_vector_type(8))) short short8;
typedef __attribute__((ext_vector_type(4))) float f32x4;

#define BB 32
#define LL 2048
#define HH 256
#define MTOT (BB*LL)          // 65536 rows
#define KK 1536               // 6 chunks * 256
#define HSIZE (MTOT*HH)       // 16777216 elements per output tensor

// chunk swizzle: row/col r, 16B-chunk q stored at q ^ SWZ4(r)  (2-way max on banks)
#define SWZ4(v) (((v) & 3) ^ (((v) >> 2) & 3))

__device__ __forceinline__ unsigned short f2bf(float f){
    unsigned u = __builtin_bit_cast(unsigned, f);
    u += 0x7FFFu + ((u >> 16) & 1u);          // round-to-nearest-even
    return (unsigned short)(u >> 16);
}
__device__ __forceinline__ unsigned pk2(float lo, float hi){
    return (unsigned)f2bf(lo) | ((unsigned)f2bf(hi) << 16);
}
__device__ __forceinline__ float sigm(float v){
    return 1.0f / (1.0f + __expf(-v));
}
__device__ __forceinline__ float ftanh(float v){
    v = fminf(fmaxf(v, -30.0f), 30.0f);
    float e = __expf(2.0f * v);
    return (e - 1.0f) / (e + 1.0f);
}
__device__ __forceinline__ void gload_lds16(const void* g, void* l){
    __builtin_amdgcn_global_load_lds(
        (const __attribute__((address_space(1))) unsigned int*)g,
        (__attribute__((address_space(3))) unsigned int*)l, 16, 0, 0);
}

// ---------------------------------------------------------------------------
// Ws [6][1536][256] f32  ->  Bt in DMA-ready, pre-swizzled tile order:
//   Bt[h_chunk][ks][j][e8]  (j = col*4 + q',  col = g*64+hc,  q' = q ^ SWZ4(col))
//   content = Ws[g][ks*32 + q*8 + e][h_chunk*64 + hc] as bf16.
// A straight global_load_lds of 1536 consecutive 16B slots per (h_chunk,ks)
// then reproduces the swizzled LDS layout the fused kernel reads.
// ---------------------------------------------------------------------------
__global__ __launch_bounds__(256) void prep_bt(const float* __restrict__ Ws,
                                               unsigned short* __restrict__ Bt){
    __shared__ float tile[64][65];
    int bid = blockIdx.x;
    int kb = bid % 24; int tmp = bid / 24; int hb = tmp & 3; int g = tmp >> 2;
    int t = threadIdx.x;
    const float* src = Ws + (size_t)g * (KK * HH) + (size_t)(kb * 64) * HH + hb * 64;
    #pragma unroll
    for (int it = 0; it < 16; ++it){
        int e = it * 256 + t; int kk = e >> 6, hh = e & 63;
        tile[kk][hh] = src[(size_t)kk * HH + hh];
    }
    __syncthreads();
    #pragma unroll
    for (int it = 0; it < 2; ++it){
        int jj  = t;                   // 0..255: slot within this gate's 256-slot range
        int ksl = it;                  // which of the two 32-k halves of this 64-k tile
        int hc  = jj >> 2, qp = jj & 3;
        int col = g * 64 + hc;
        int q   = qp ^ SWZ4(col);
        int kbase = ksl * 32 + q * 8;
        unsigned wz[4];
        #pragma unroll
        for (int p = 0; p < 4; ++p)
            wz[p] = pk2(tile[kbase + 2*p][hc], tile[kbase + 2*p + 1][hc]);
        int ksg = kb * 2 + ksl;
        size_t off = ((size_t)(hb * 48 + ksg) * 1536 + (size_t)g * 256 + jj) * 8;
        *(uint4*)&Bt[off] = *(uint4*)wz;
    }
}

// ---------------------------------------------------------------------------
// Fused GEMM (bf16 MFMA) + sLSTM epilogue.
// Block tile: 128 rows x (6 gates x 64 h). 8 waves: wave = 64 rows x (6g x 16h).
// Double-buffered LDS, ONE barrier per K-step:
//   stage(k+1): A f32 loads issued early, packed+ds_written after MFMAs (T14);
//               B via 3x global_load_lds into the pre-swizzled DMA layout.
//   compute(k): swizzled ds_read_b128 fragments (2-way banks max) + 24 MFMA.
// ---------------------------------------------------------------------------
__global__ __launch_bounds__(512, 2) void slstm_fused(
    const float* __restrict__ h_t, const float* __restrict__ x,
    const float* __restrict__ h_slot, const float* __restrict__ h_intent,
    const float* __restrict__ c_t, const float* __restrict__ bs,
    const unsigned short* __restrict__ Bt, float* __restrict__ out)
{
    __shared__ __align__(16) unsigned short As[2][128 * 32];   // 8 KB per buffer
    __shared__ __align__(16) unsigned short Bs[2][384 * 32];   // 24 KB per buffer

    const int t    = threadIdx.x;
    const int wv   = t >> 6,  ln  = t & 63;
    const int rg   = wv >> 2, ht  = wv & 3;      // row-group (0/1), h-tile (0..3)
    const int quad = ln >> 4, l16 = ln & 15;

    // XCD-aware bijective swizzle: 2048 blocks -> 256 contiguous per XCD, so the
    // 4 h_chunk blocks of an m_block share one XCD's L2 (A panel fetched once).
    const int rawb = blockIdx.x;
    const int vb   = (rawb & 7) * 256 + (rawb >> 3);
    const int h_chunk = vb & 3;                  // h fastest within an XCD chunk
    const int m_block = vb >> 2;
    const int h0      = h_chunk * 64;

    // A-staging coords: thread -> (row 0..127, 8 consecutive k)
    const int  arow = t >> 2;
    const int  aq   = t & 3;
    const int  akq  = aq << 3;                   // k offset 0,8,16,24
    const long mg   = (long)m_block * 128 + arow;
    const int  lseq = (int)(mg & (LL - 1));
    const int  awq  = (aq ^ SWZ4(arow)) << 3;    // swizzled write chunk (shorts)
    const int  qa   = (quad ^ SWZ4(l16)) << 3;   // swizzled read chunk (shorts)

    const unsigned short* BtH = Bt + (size_t)h_chunk * 48 * 1536 * 8;

    f32x4 acc[4][6] = {};                        // [m-tile][gate]

    float4 av0, av1;
    auto stageA_issue = [&](int ks){
        int c  = ks >> 3;                        // which of the 6 cat chunks
        int kk = ((ks & 7) << 5) + akq;
        const float* src; int sh;
        switch (c){
            case 0:  src = h_t;      sh =  0; break;
            case 1:  src = h_t;      sh = -1; break;   // h_left
            case 2:  src = h_t;      sh =  1; break;   // h_right
            case 3:  src = x;        sh =  0; break;
            case 4:  src = h_slot;   sh =  0; break;
            default: src = h_intent; sh =  0; break;
        }
        int sl = lseq + sh;
        av0 = make_float4(0.f,0.f,0.f,0.f); av1 = av0;
        if ((unsigned)sl < (unsigned)LL){
            const float* p = src + ((mg + sh) * HH + kk);
            av0 = *(const float4*)p;
            av1 = *(const float4*)(p + 4);
        }
    };
    auto stageB = [&](int buf, int ks){
        const unsigned short* gsrc = BtH + (size_t)ks * 1536 * 8;
        #pragma unroll
        for (int i = 0; i < 3; ++i){
            gload_lds16(gsrc + (size_t)(i * 512 + t) * 8,
                        &Bs[buf][(i * 512 + wv * 64) * 8]);
        }
    };
    auto stageA_write = [&](int buf){
        uint4 w;
        w.x = pk2(av0.x, av0.y); w.y = pk2(av0.z, av0.w);
        w.z = pk2(av1.x, av1.y); w.w = pk2(av1.z, av1.w);
        *(uint4*)&As[buf][arow * 32 + awq] = w;
    };

    // prologue: fill buffer 0
    stageA_issue(0);
    stageB(0, 0);
    stageA_write(0);
    __syncthreads();

    for (int ks = 0; ks < 48; ++ks){
        const int cur = ks & 1, nxt = cur ^ 1;
        if (ks < 47){
            stageA_issue(ks + 1);                // f32 loads in flight over compute
            stageB(nxt, ks + 1);                 // DMA in flight over compute
        }
        short8 a[4];
        #pragma unroll
        for (int mt = 0; mt < 4; ++mt)
            a[mt] = *(const short8*)&As[cur][(rg * 64 + mt * 16 + l16) * 32 + qa];
        #pragma unroll
        for (int g = 0; g < 6; ++g){
            short8 bfrag = *(const short8*)&Bs[cur][(g * 64 + ht * 16 + l16) * 32 + qa];
            #pragma unroll
            for (int mt = 0; mt < 4; ++mt)
                acc[mt][g] = __builtin_amdgcn_mfma_f32_16x16x32_bf16(a[mt], bfrag, acc[mt][g], 0, 0, 0);
        }
        if (ks < 47) stageA_write(nxt);          // pack + ds_write after MFMAs
        __syncthreads();                          // single barrier per K-step
    }

    // ---- epilogue: all 6 gates for (row,h) live in this lane ----
    const int h = h0 + ht * 16 + l16;
    float bias[6];
    #pragma unroll
    for (int g = 0; g < 6; ++g) bias[g] = bs[g * HH + h];

    #pragma unroll
    for (int mt = 0; mt < 4; ++mt){
        #pragma unroll
        for (int r = 0; r < 4; ++r){
            long row = (long)m_block * 128 + rg * 64 + mt * 16 + quad * 4 + r;
            int  ls  = (int)(row & (LL - 1));
            float gi = sigm(acc[mt][0][r] + bias[0]);
            float go = sigm(acc[mt][1][r] + bias[1]);
            float gf = sigm(acc[mt][2][r] + bias[2]);
            float gl = sigm(acc[mt][3][r] + bias[3]);
            float gr = sigm(acc[mt][4][r] + bias[4]);
            float gu = ftanh(acc[mt][5][r] + bias[5]);
            // softmax over the sigmoid outputs [i, f, l, r]
            float ei = __expf(gi), ef = __expf(gf), el = __expf(gl), er = __expf(gr);
            float inv = 1.0f / (ei + ef + el + er);
            float cm  = c_t[row * HH + h];
            float clv = (ls > 0)      ? c_t[(row - 1) * HH + h] : 0.0f;
            float crv = (ls < LL - 1) ? c_t[(row + 1) * HH + h] : 0.0f;
            float cn  = (ef * cm + el * clv + er * crv + ei * gu) * inv;
            float hn  = go * ftanh(cn);
            out[row * HH + h]         = hn;
            out[HSIZE + row * HH + h] = cn;
        }
    }
}

extern "C" void kernel_launch(void* const* d_in, const int* in_sizes, int n_in,
                              void* d_out, int out_size, void* d_ws, size_t ws_size,
                              hipStream_t stream){
    const float* h_t      = (const float*)d_in[0];
    const float* x        = (const float*)d_in[1];
    const float* h_slot   = (const float*)d_in[2];
    const float* h_intent = (const float*)d_in[3];
    const float* c_t      = (const float*)d_in[4];
    const float* Ws       = (const float*)d_in[5];
    const float* bs       = (const float*)d_in[6];
    unsigned short* Bt    = (unsigned short*)d_ws;   // 1536*1536 bf16 = 4.7 MB

    prep_bt<<<576, 256, 0, stream>>>(Ws, Bt);
    slstm_fused<<<2048, 512, 0, stream>>>(h_t, x, h_slot, h_intent, c_t, bs, Bt, (float*)d_out);
}